// Round 10
// baseline (664.477 us; speedup 1.0000x reference)
//
#include <hip/hip_runtime.h>
#include <math.h>

#define HW 4096      // 64*64
#define CS 32        // channels per branch
#define NS 128       // B*GROUPS samples
#define NPLANES 8192 // NS * 64
#define EPS 1e-5f

__device__ __forceinline__ float sigmoidf_(float x) {
    return 1.0f / (1.0f + __expf(-x));
}

// One block per plane, 8192 blocks (oversubscribed). Group = 32 consecutive
// blocks = the planes of one (sample, branch). x staged in registers across
// the group sync -> x read exactly once, output written from registers.
// Sync: relaxed-poll + s_sleep (NO acquire-per-poll: R6's L2-invalidate storm),
// one acquire on exit (R8-proven correct).
__global__ __launch_bounds__(256) void fused_pipe(
    const float* __restrict__ x, float* __restrict__ out,
    const float* __restrict__ cw,  const float* __restrict__ cb,
    const float* __restrict__ sw,  const float* __restrict__ sb,
    const float* __restrict__ gnw, const float* __restrict__ gnb,
    const float* __restrict__ fc1w, const float* __restrict__ fc1b,
    const float* __restrict__ lnw, const float* __restrict__ lnb,
    const float* __restrict__ fc2w, const float* __restrict__ fc2b,
    float* __restrict__ pvbuf, unsigned int* __restrict__ cnt) {
    const int P = blockIdx.x;
    const int cc = P & 63;           // plane within sample (block-uniform)
    const int branch = cc >> 5;      // 0: channel-att, 1: spatial
    const int c = cc & 31;           // channel within branch
    const int g = P >> 5;            // group id 0..255
    const int tid = threadIdx.x;
    const int wave = tid >> 6, lane = tid & 63;

    __shared__ float ls[4], ls2[4];
    __shared__ float bcmu, bcrs, bcg0, bcsc;

    // ---- phase 1: load plane into registers + sum/sumsq ----
    const float4* xp = (const float4*)x + (size_t)P * 1024;
    float4 v[4];
    float s = 0.f, s2 = 0.f;
#pragma unroll
    for (int k = 0; k < 4; ++k) {
        v[k] = xp[tid + k * 256];
        s  += v[k].x + v[k].y + v[k].z + v[k].w;
        s2 += v[k].x * v[k].x + v[k].y * v[k].y
            + v[k].z * v[k].z + v[k].w * v[k].w;
    }
    for (int off = 32; off; off >>= 1) {
        s  += __shfl_down(s,  off, 64);
        s2 += __shfl_down(s2, off, 64);
    }
    if (lane == 0) { ls[wave] = s; ls2[wave] = s2; }
    __syncthreads();

    if (branch == 0) {
        if (tid == 0) {
            float mean = (ls[0] + ls[1] + ls[2] + ls[3]) * (1.0f / HW);
            float g0 = sigmoidf_(cw[c] * mean + cb[c]);
            bcg0 = g0;
            float pv = mean * (1.0f - g0);          // mean of x_reid_0
            __hip_atomic_store(&pvbuf[P], pv,
                               __ATOMIC_RELAXED, __HIP_MEMORY_SCOPE_AGENT);
            __hip_atomic_fetch_add(&cnt[g], 1u,
                                   __ATOMIC_RELEASE, __HIP_MEMORY_SCOPE_AGENT);
        }
    } else {
        if (tid == 0) {
            float mu  = (ls[0] + ls[1] + ls[2] + ls[3]) * (1.0f / HW);
            float var = (ls2[0] + ls2[1] + ls2[2] + ls2[3]) * (1.0f / HW) - mu * mu;
            bcmu = mu;
            bcrs = rsqrtf(var + EPS);
        }
        __syncthreads();
        const float mu = bcmu, rs = bcrs;
        const float a   = gnw[c] * rs;
        const float b0  = gnb[c] - mu * a;
        const float sbv = sb[c];
        const float4* wp = (const float4*)sw + (size_t)c * 1024;
        float sx = 0.f;
#pragma unroll
        for (int k = 0; k < 4; ++k) {
            float4 w = wp[tid + k * 256];
            sx += v[k].x * sigmoidf_(w.x * (v[k].x * a + b0) + sbv);
            sx += v[k].y * sigmoidf_(w.y * (v[k].y * a + b0) + sbv);
            sx += v[k].z * sigmoidf_(w.z * (v[k].z * a + b0) + sbv);
            sx += v[k].w * sigmoidf_(w.w * (v[k].w * a + b0) + sbv);
        }
        for (int off = 32; off; off >>= 1) sx += __shfl_down(sx, off, 64);
        if (lane == 0) ls[wave] = sx;
        __syncthreads();
        if (tid == 0) {
            float sxt = ls[0] + ls[1] + ls[2] + ls[3];
            float pv = bcmu - sxt * (1.0f / HW);    // mean of x_reid_1
            __hip_atomic_store(&pvbuf[P], pv,
                               __ATOMIC_RELAXED, __HIP_MEMORY_SCOPE_AGENT);
            __hip_atomic_fetch_add(&cnt[g], 1u,
                                   __ATOMIC_RELEASE, __HIP_MEMORY_SCOPE_AGENT);
        }
    }

    // ---- group sync: relaxed poll (no cache invalidation), one acquire ----
    if (tid == 0) {
        int spins = 0;
        while (__hip_atomic_load(&cnt[g], __ATOMIC_RELAXED,
                                 __HIP_MEMORY_SCOPE_AGENT) < 32u
               && ++spins < (1 << 17))
            __builtin_amdgcn_s_sleep(16);
        (void)__hip_atomic_load(&cnt[g], __ATOMIC_ACQUIRE,
                                __HIP_MEMORY_SCOPE_AGENT);
    }
    __syncthreads();

    // ---- gate MLP: wave 0, shuffle-based (lanes 32-63 duplicate 0-31) ----
    if (wave == 0) {
        const int l = lane & 31;
        float pv = pvbuf[(P & ~31) + l];
        float qv = fc1b[l];
#pragma unroll 8
        for (int j = 0; j < CS; ++j)
            qv += fc1w[l * CS + j] * __shfl(pv, (lane & 32) + j, 64);
        float bs = qv, bs2 = qv * qv;
        for (int m = 1; m < 32; m <<= 1) {   // stays within each 32-lane half
            bs  += __shfl_xor(bs,  m, 64);
            bs2 += __shfl_xor(bs2, m, 64);
        }
        float mu  = bs * (1.0f / CS);
        float var = bs2 * (1.0f / CS) - mu * mu;
        float r   = fmaxf((qv - mu) * rsqrtf(var + EPS) * lnw[l] + lnb[l], 0.f);
        float sv  = fc2b[l];
#pragma unroll 8
        for (int j = 0; j < CS; ++j)
            sv += fc2w[l * CS + j] * __shfl(r, (lane & 32) + j, 64);
        float gd  = sigmoidf_(sv);
        float gdc = __shfl(gd, c, 64);       // this block's channel
        if (tid == 0) bcsc = branch ? gdc : (bcg0 + (1.0f - bcg0) * gdc);
    }
    __syncthreads();

    // ---- output from staged registers (x never re-read) ----
    const float sc = bcsc;
    float4* op = (float4*)out + (size_t)P * 1024;
    if (branch == 0) {
#pragma unroll
        for (int k = 0; k < 4; ++k) {
            float4 o = v[k];
            o.x *= sc; o.y *= sc; o.z *= sc; o.w *= sc;
            op[tid + k * 256] = o;
        }
    } else {
        const float mu = bcmu, rs = bcrs;
        const float a   = gnw[c] * rs;
        const float b0  = gnb[c] - mu * a;
        const float sbv = sb[c];
        const float4* wp = (const float4*)sw + (size_t)c * 1024;
#pragma unroll
        for (int k = 0; k < 4; ++k) {
            float4 w = wp[tid + k * 256];    // same addrs as phase 2: L1/L2-hot
            float4 o; float sg;
            sg = sigmoidf_(w.x * (v[k].x * a + b0) + sbv); o.x = v[k].x * (sg + (1.f - sg) * sc);
            sg = sigmoidf_(w.y * (v[k].y * a + b0) + sbv); o.y = v[k].y * (sg + (1.f - sg) * sc);
            sg = sigmoidf_(w.z * (v[k].z * a + b0) + sbv); o.z = v[k].z * (sg + (1.f - sg) * sc);
            sg = sigmoidf_(w.w * (v[k].w * a + b0) + sbv); o.w = v[k].w * (sg + (1.f - sg) * sc);
            op[tid + k * 256] = o;
        }
    }
}

extern "C" void kernel_launch(void* const* d_in, const int* in_sizes, int n_in,
                              void* d_out, int out_size, void* d_ws, size_t ws_size,
                              hipStream_t stream) {
    const float* x    = (const float*)d_in[0];
    const float* cw   = (const float*)d_in[1];
    const float* cb   = (const float*)d_in[2];
    const float* sw   = (const float*)d_in[3];
    const float* sb   = (const float*)d_in[4];
    const float* gnw  = (const float*)d_in[5];
    const float* gnb  = (const float*)d_in[6];
    const float* fc1w = (const float*)d_in[7];
    const float* fc1b = (const float*)d_in[8];
    const float* lnw  = (const float*)d_in[9];
    const float* lnb  = (const float*)d_in[10];
    const float* fc2w = (const float*)d_in[11];
    const float* fc2b = (const float*)d_in[12];
    float* out = (float*)d_out;

    unsigned int* cnt = (unsigned int*)d_ws;           // 256 counters (1 KiB)
    float* pvbuf      = (float*)((char*)d_ws + 1024);  // 8192 floats

    hipMemsetAsync(cnt, 0, 1024, stream);              // re-zero every call
    fused_pipe<<<NPLANES, 256, 0, stream>>>(x, out, cw, cb, sw, sb,
                                            gnw, gnb, fc1w, fc1b,
                                            lnw, lnb, fc2w, fc2b,
                                            pvbuf, cnt);
}

// Round 11
// 81.211 us; speedup vs baseline: 8.1821x; 8.1821x over previous
//
#include <hip/hip_runtime.h>
#include <math.h>

#define HW 4096      // 64*64
#define CS 32        // channels per branch
#define NS 128       // B*GROUPS samples
#define NPLANES 8192 // NS * 64
#define EPS 1e-5f
#define SENT 0x7F7F7F7Fu   // 3.39e38f: unreachable by any pv value

__device__ __forceinline__ float sigmoidf_(float x) {
    return 1.0f / (1.0f + __expf(-x));
}

// One block per plane, 8192 blocks. Group = 32 consecutive blocks = planes of
// one (sample, branch) -> co-dispatched, branch-homogeneous. x staged in regs
// across the group handshake; output written from regs (x read exactly once).
// Handshake: sentinel-payload, RELAXED agent atomics only (no release/acquire
// -> no buffer_wbl2 / L2-invalidate storms, the R6/R10 killer).
__global__ __launch_bounds__(256) void fused_sentinel(
    const float* __restrict__ x, float* __restrict__ out,
    const float* __restrict__ cw,  const float* __restrict__ cb,
    const float* __restrict__ sw,  const float* __restrict__ sb,
    const float* __restrict__ gnw, const float* __restrict__ gnb,
    const float* __restrict__ fc1w, const float* __restrict__ fc1b,
    const float* __restrict__ lnw, const float* __restrict__ lnb,
    const float* __restrict__ fc2w, const float* __restrict__ fc2b,
    unsigned int* __restrict__ pvbuf) {
    const int P = blockIdx.x;
    const int cc = P & 63;           // plane within sample
    const int branch = cc >> 5;      // group is branch-homogeneous
    const int c = cc & 31;
    const int tid = threadIdx.x;
    const int wave = tid >> 6, lane = tid & 63;

    __shared__ float ls[4], ls2[4];
    __shared__ float bcmu, bcrs, bcg0, bcsc;

    // ---- phase 1: load plane into registers + sum/sumsq ----
    const float4* xp = (const float4*)x + (size_t)P * 1024;
    float4 v[4];
    float s = 0.f, s2 = 0.f;
#pragma unroll
    for (int k = 0; k < 4; ++k) {
        v[k] = xp[tid + k * 256];
        s  += v[k].x + v[k].y + v[k].z + v[k].w;
        s2 += v[k].x * v[k].x + v[k].y * v[k].y
            + v[k].z * v[k].z + v[k].w * v[k].w;
    }
    // pin staged values in VGPRs: forbid rematerializing the loads later
#pragma unroll
    for (int k = 0; k < 4; ++k)
        asm volatile("" : "+v"(v[k].x), "+v"(v[k].y), "+v"(v[k].z), "+v"(v[k].w));

    for (int off = 32; off; off >>= 1) {
        s  += __shfl_down(s,  off, 64);
        s2 += __shfl_down(s2, off, 64);
    }
    if (lane == 0) { ls[wave] = s; ls2[wave] = s2; }
    __syncthreads();

    if (branch == 0) {
        if (tid == 0) {
            float mean = (ls[0] + ls[1] + ls[2] + ls[3]) * (1.0f / HW);
            float g0 = sigmoidf_(cw[c] * mean + cb[c]);
            bcg0 = g0;
            float pv = mean * (1.0f - g0);          // mean of x_reid_0
            __hip_atomic_store(&pvbuf[P], __float_as_uint(pv),
                               __ATOMIC_RELAXED, __HIP_MEMORY_SCOPE_AGENT);
        }
    } else {
        if (tid == 0) {
            float mu  = (ls[0] + ls[1] + ls[2] + ls[3]) * (1.0f / HW);
            float var = (ls2[0] + ls2[1] + ls2[2] + ls2[3]) * (1.0f / HW) - mu * mu;
            bcmu = mu;
            bcrs = rsqrtf(var + EPS);
        }
        __syncthreads();
        const float mu = bcmu, rs = bcrs;
        const float a   = gnw[c] * rs;
        const float b0  = gnb[c] - mu * a;
        const float sbv = sb[c];
        const float4* wp = (const float4*)sw + (size_t)c * 1024;
        float sx = 0.f;
#pragma unroll
        for (int k = 0; k < 4; ++k) {
            float4 w = wp[tid + k * 256];
            sx += v[k].x * sigmoidf_(w.x * (v[k].x * a + b0) + sbv);
            sx += v[k].y * sigmoidf_(w.y * (v[k].y * a + b0) + sbv);
            sx += v[k].z * sigmoidf_(w.z * (v[k].z * a + b0) + sbv);
            sx += v[k].w * sigmoidf_(w.w * (v[k].w * a + b0) + sbv);
        }
        for (int off = 32; off; off >>= 1) sx += __shfl_down(sx, off, 64);
        if (lane == 0) ls[wave] = sx;
        __syncthreads();
        if (tid == 0) {
            float sxt = ls[0] + ls[1] + ls[2] + ls[3];
            float pv = bcmu - sxt * (1.0f / HW);    // mean of x_reid_1
            __hip_atomic_store(&pvbuf[P], __float_as_uint(pv),
                               __ATOMIC_RELAXED, __HIP_MEMORY_SCOPE_AGENT);
        }
    }

    // ---- group handshake + gate MLP (wave 0; lane l polls sibling slot l) ----
    if (wave == 0) {
        const int l = lane & 31;
        const unsigned int* slot = &pvbuf[(P & ~31) + l];
        unsigned int bits = __hip_atomic_load(slot, __ATOMIC_RELAXED,
                                              __HIP_MEMORY_SCOPE_AGENT);
        int spins = 0;
        while (__any(bits == SENT) && ++spins < (1 << 18)) {
            __builtin_amdgcn_s_sleep(2);
            bits = __hip_atomic_load(slot, __ATOMIC_RELAXED,
                                     __HIP_MEMORY_SCOPE_AGENT);
        }
        float pv = __uint_as_float(bits);

        float qv = fc1b[l];
#pragma unroll 8
        for (int j = 0; j < CS; ++j)
            qv += fc1w[l * CS + j] * __shfl(pv, (lane & 32) + j, 64);
        float bs = qv, bs2 = qv * qv;
        for (int m = 1; m < 32; m <<= 1) {   // stays within each 32-lane half
            bs  += __shfl_xor(bs,  m, 64);
            bs2 += __shfl_xor(bs2, m, 64);
        }
        float mu  = bs * (1.0f / CS);
        float var = bs2 * (1.0f / CS) - mu * mu;
        float r   = fmaxf((qv - mu) * rsqrtf(var + EPS) * lnw[l] + lnb[l], 0.f);
        float sv  = fc2b[l];
#pragma unroll 8
        for (int j = 0; j < CS; ++j)
            sv += fc2w[l * CS + j] * __shfl(r, (lane & 32) + j, 64);
        float gd  = sigmoidf_(sv);
        float gdc = __shfl(gd, c, 64);       // this block's channel
        if (tid == 0) bcsc = branch ? gdc : (bcg0 + (1.0f - bcg0) * gdc);
    }
    __syncthreads();

    // ---- output from staged registers (x never re-read) ----
    const float sc = bcsc;
    float4* op = (float4*)out + (size_t)P * 1024;
    if (branch == 0) {
#pragma unroll
        for (int k = 0; k < 4; ++k) {
            float4 o = v[k];
            o.x *= sc; o.y *= sc; o.z *= sc; o.w *= sc;
            op[tid + k * 256] = o;
        }
    } else {
        const float mu = bcmu, rs = bcrs;
        const float a   = gnw[c] * rs;
        const float b0  = gnb[c] - mu * a;
        const float sbv = sb[c];
        const float4* wp = (const float4*)sw + (size_t)c * 1024;
#pragma unroll
        for (int k = 0; k < 4; ++k) {
            float4 w = wp[tid + k * 256];    // same addrs as phase 2: L1/L2-hot
            float4 o; float sg;
            sg = sigmoidf_(w.x * (v[k].x * a + b0) + sbv); o.x = v[k].x * (sg + (1.f - sg) * sc);
            sg = sigmoidf_(w.y * (v[k].y * a + b0) + sbv); o.y = v[k].y * (sg + (1.f - sg) * sc);
            sg = sigmoidf_(w.z * (v[k].z * a + b0) + sbv); o.z = v[k].z * (sg + (1.f - sg) * sc);
            sg = sigmoidf_(w.w * (v[k].w * a + b0) + sbv); o.w = v[k].w * (sg + (1.f - sg) * sc);
            op[tid + k * 256] = o;
        }
    }
}

extern "C" void kernel_launch(void* const* d_in, const int* in_sizes, int n_in,
                              void* d_out, int out_size, void* d_ws, size_t ws_size,
                              hipStream_t stream) {
    const float* x    = (const float*)d_in[0];
    const float* cw   = (const float*)d_in[1];
    const float* cb   = (const float*)d_in[2];
    const float* sw   = (const float*)d_in[3];
    const float* sb   = (const float*)d_in[4];
    const float* gnw  = (const float*)d_in[5];
    const float* gnb  = (const float*)d_in[6];
    const float* fc1w = (const float*)d_in[7];
    const float* fc1b = (const float*)d_in[8];
    const float* lnw  = (const float*)d_in[9];
    const float* lnb  = (const float*)d_in[10];
    const float* fc2w = (const float*)d_in[11];
    const float* fc2b = (const float*)d_in[12];
    float* out = (float*)d_out;

    unsigned int* pvbuf = (unsigned int*)d_ws;   // 8192 slots (32 KiB)

    // every byte 0x7F -> every slot == SENT; capturable async memset
    hipMemsetAsync(pvbuf, 0x7F, NPLANES * sizeof(unsigned int), stream);
    fused_sentinel<<<NPLANES, 256, 0, stream>>>(x, out, cw, cb, sw, sb,
                                                gnw, gnb, fc1w, fc1b,
                                                lnw, lnb, fc2w, fc2b, pvbuf);
}

// Round 12
// 76.025 us; speedup vs baseline: 8.7402x; 1.0682x over previous
//
#include <hip/hip_runtime.h>
#include <math.h>

#define HW 4096      // 64*64
#define CS 32        // channels per branch
#define NS 128       // B*GROUPS samples
#define NBLK 4096    // one block = channel c of BOTH branches of sample n
#define EPS 1e-5f
#define SENT 0x7F7F7F7Fu   // 3.39e38f: unreachable by any pv value

__device__ __forceinline__ float sigmoidf_(float x) {
    return 1.0f / (1.0f + __expf(-x));
}

// Block B: sample n=B>>5, channel c=B&31; owns plane (n,c) of branch0 AND
// plane (n,32+c) of branch1. Both staged in regs (32 VGPR) -> x read once.
// Uniform per-block work (no branch imbalance), 2 dispatch generations.
// Group = 32 consecutive blocks (one sample). Handshake: sentinel payload,
// RELAXED agent atomics only (R11-proven: no L2 wb/inv storms).
__global__ __launch_bounds__(256) void fused_pair(
    const float* __restrict__ x, float* __restrict__ out,
    const float* __restrict__ cw,  const float* __restrict__ cb,
    const float* __restrict__ sw,  const float* __restrict__ sb,
    const float* __restrict__ gnw, const float* __restrict__ gnb,
    const float* __restrict__ fc1w, const float* __restrict__ fc1b,
    const float* __restrict__ lnw, const float* __restrict__ lnb,
    const float* __restrict__ fc2w, const float* __restrict__ fc2b,
    unsigned int* __restrict__ pvbuf) {
    const int B = blockIdx.x;
    const int n = B >> 5, c = B & 31;
    const int tid = threadIdx.x;
    const int wave = tid >> 6, lane = tid & 63;

    __shared__ float lsA[4], lsB[4], lsC[4];
    __shared__ float bcmu, bcrs, bcg0, bcsc0, bcsc1;

    const float4* xp0 = (const float4*)x + (size_t)(n * 64 + c) * 1024;
    const float4* xp1 = (const float4*)x + (size_t)(n * 64 + CS + c) * 1024;

    // ---- phase 1: stage both planes (32 VGPR), three sums in one pass ----
    float4 v0[4], v1[4];
#pragma unroll
    for (int k = 0; k < 4; ++k) { v0[k] = xp0[tid + k * 256]; v1[k] = xp1[tid + k * 256]; }
#pragma unroll
    for (int k = 0; k < 4; ++k) {   // pin staged values in VGPRs
        asm volatile("" : "+v"(v0[k].x), "+v"(v0[k].y), "+v"(v0[k].z), "+v"(v0[k].w));
        asm volatile("" : "+v"(v1[k].x), "+v"(v1[k].y), "+v"(v1[k].z), "+v"(v1[k].w));
    }
    float s0 = 0.f, s1 = 0.f, q1 = 0.f;
#pragma unroll
    for (int k = 0; k < 4; ++k) {
        s0 += v0[k].x + v0[k].y + v0[k].z + v0[k].w;
        s1 += v1[k].x + v1[k].y + v1[k].z + v1[k].w;
        q1 += v1[k].x * v1[k].x + v1[k].y * v1[k].y
            + v1[k].z * v1[k].z + v1[k].w * v1[k].w;
    }
    for (int off = 32; off; off >>= 1) {
        s0 += __shfl_down(s0, off, 64);
        s1 += __shfl_down(s1, off, 64);
        q1 += __shfl_down(q1, off, 64);
    }
    if (lane == 0) { lsA[wave] = s0; lsB[wave] = s1; lsC[wave] = q1; }
    __syncthreads();
    if (tid == 0) {
        float sum0 = lsA[0] + lsA[1] + lsA[2] + lsA[3];
        float sum1 = lsB[0] + lsB[1] + lsB[2] + lsB[3];
        float sq1  = lsC[0] + lsC[1] + lsC[2] + lsC[3];
        float mean0 = sum0 * (1.0f / HW);
        float g0 = sigmoidf_(cw[c] * mean0 + cb[c]);
        bcg0 = g0;
        // publish branch0 pv EARLY (shortens siblings' spin)
        __hip_atomic_store(&pvbuf[n * 64 + c],
                           __float_as_uint(mean0 * (1.0f - g0)),
                           __ATOMIC_RELAXED, __HIP_MEMORY_SCOPE_AGENT);
        float mu  = sum1 * (1.0f / HW);
        float var = sq1 * (1.0f / HW) - mu * mu;
        bcmu = mu;
        bcrs = rsqrtf(var + EPS);
    }
    __syncthreads();

    // ---- phase 2: sum(xs) on the branch1 plane (from regs; sw L2-hot) ----
    const float mu = bcmu, rs = bcrs;
    const float a   = gnw[c] * rs;
    const float b0  = gnb[c] - mu * a;
    const float sbv = sb[c];
    const float4* wp = (const float4*)sw + (size_t)c * 1024;
    float sx = 0.f;
#pragma unroll
    for (int k = 0; k < 4; ++k) {
        float4 w = wp[tid + k * 256];
        sx += v1[k].x * sigmoidf_(w.x * (v1[k].x * a + b0) + sbv);
        sx += v1[k].y * sigmoidf_(w.y * (v1[k].y * a + b0) + sbv);
        sx += v1[k].z * sigmoidf_(w.z * (v1[k].z * a + b0) + sbv);
        sx += v1[k].w * sigmoidf_(w.w * (v1[k].w * a + b0) + sbv);
    }
    for (int off = 32; off; off >>= 1) sx += __shfl_down(sx, off, 64);
    if (lane == 0) lsA[wave] = sx;
    __syncthreads();
    if (tid == 0) {
        float sxt = lsA[0] + lsA[1] + lsA[2] + lsA[3];
        __hip_atomic_store(&pvbuf[n * 64 + CS + c],
                           __float_as_uint(mu - sxt * (1.0f / HW)),
                           __ATOMIC_RELAXED, __HIP_MEMORY_SCOPE_AGENT);
    }

    // ---- handshake + dual gate MLP (wave 0; lane l owns slot n*64+l) ----
    if (wave == 0) {
        const int l = lane & 31;
        const unsigned int* slot = &pvbuf[n * 64 + lane];
        unsigned int bits = __hip_atomic_load(slot, __ATOMIC_RELAXED,
                                              __HIP_MEMORY_SCOPE_AGENT);
        int spins = 0;
        while (__any(bits == SENT) && ++spins < (1 << 18)) {
            __builtin_amdgcn_s_sleep(2);
            bits = __hip_atomic_load(slot, __ATOMIC_RELAXED,
                                     __HIP_MEMORY_SCOPE_AGENT);
        }
        float pv = __uint_as_float(bits);

        float qv = fc1b[l];
#pragma unroll 8
        for (int j = 0; j < CS; ++j)
            qv += fc1w[l * CS + j] * __shfl(pv, (lane & 32) + j, 64);
        float bs = qv, bs2 = qv * qv;
        for (int m = 1; m < 32; m <<= 1) {   // stays within each 32-lane half
            bs  += __shfl_xor(bs,  m, 64);
            bs2 += __shfl_xor(bs2, m, 64);
        }
        float muq  = bs * (1.0f / CS);
        float varq = bs2 * (1.0f / CS) - muq * muq;
        float r    = fmaxf((qv - muq) * rsqrtf(varq + EPS) * lnw[l] + lnb[l], 0.f);
        float sv   = fc2b[l];
#pragma unroll 8
        for (int j = 0; j < CS; ++j)
            sv += fc2w[l * CS + j] * __shfl(r, (lane & 32) + j, 64);
        float gd  = sigmoidf_(sv);
        float gd0 = __shfl(gd, c, 64);        // branch0 gate for channel c
        float gd1 = __shfl(gd, CS + c, 64);   // branch1 gate for channel c
        if (tid == 0) {
            bcsc0 = bcg0 + (1.0f - bcg0) * gd0;
            bcsc1 = gd1;
        }
    }
    __syncthreads();

    // ---- outputs from staged registers (x never re-read) ----
    const float sc0 = bcsc0, sc1 = bcsc1;
    float4* op0 = (float4*)out + (size_t)(n * 64 + c) * 1024;
    float4* op1 = (float4*)out + (size_t)(n * 64 + CS + c) * 1024;
#pragma unroll
    for (int k = 0; k < 4; ++k) {
        float4 o = v0[k];
        o.x *= sc0; o.y *= sc0; o.z *= sc0; o.w *= sc0;
        op0[tid + k * 256] = o;
    }
#pragma unroll
    for (int k = 0; k < 4; ++k) {
        float4 w = wp[tid + k * 256];   // same addrs as phase 2: L1-hot
        float4 o; float sg;
        sg = sigmoidf_(w.x * (v1[k].x * a + b0) + sbv); o.x = v1[k].x * (sg + (1.f - sg) * sc1);
        sg = sigmoidf_(w.y * (v1[k].y * a + b0) + sbv); o.y = v1[k].y * (sg + (1.f - sg) * sc1);
        sg = sigmoidf_(w.z * (v1[k].z * a + b0) + sbv); o.z = v1[k].z * (sg + (1.f - sg) * sc1);
        sg = sigmoidf_(w.w * (v1[k].w * a + b0) + sbv); o.w = v1[k].w * (sg + (1.f - sg) * sc1);
        op1[tid + k * 256] = o;
    }
}

extern "C" void kernel_launch(void* const* d_in, const int* in_sizes, int n_in,
                              void* d_out, int out_size, void* d_ws, size_t ws_size,
                              hipStream_t stream) {
    const float* x    = (const float*)d_in[0];
    const float* cw   = (const float*)d_in[1];
    const float* cb   = (const float*)d_in[2];
    const float* sw   = (const float*)d_in[3];
    const float* sb   = (const float*)d_in[4];
    const float* gnw  = (const float*)d_in[5];
    const float* gnb  = (const float*)d_in[6];
    const float* fc1w = (const float*)d_in[7];
    const float* fc1b = (const float*)d_in[8];
    const float* lnw  = (const float*)d_in[9];
    const float* lnb  = (const float*)d_in[10];
    const float* fc2w = (const float*)d_in[11];
    const float* fc2b = (const float*)d_in[12];
    float* out = (float*)d_out;

    unsigned int* pvbuf = (unsigned int*)d_ws;   // 8192 slots (32 KiB)

    // every byte 0x7F -> every slot == SENT; capturable async memset
    hipMemsetAsync(pvbuf, 0x7F, 8192 * sizeof(unsigned int), stream);
    fused_pair<<<NBLK, 256, 0, stream>>>(x, out, cw, cb, sw, sb,
                                         gnw, gnb, fc1w, fc1b,
                                         lnw, lnb, fc2w, fc2b, pvbuf);
}